// Round 11
// baseline (32.354 us; speedup 1.0000x reference)
//
#include <hip/hip_runtime.h>
#include <math.h>

#define HW_   6688      // 44*152
#define W_    152
#define NPIX  107008    // 16*44*152
#define OW_   1216      // 152*8
#define OHW_  428032    // 352*1216

typedef _Float16 f16;
typedef _Float16 f16x2 __attribute__((ext_vector_type(2)));
typedef _Float16 f16x4 __attribute__((ext_vector_type(4)));
typedef _Float16 f16x8 __attribute__((ext_vector_type(8)));
typedef float    f32x4 __attribute__((ext_vector_type(4)));

#define MFMA(a,b,c) __builtin_amdgcn_mfma_f32_16x16x32_f16((a),(b),(c),0,0,0)

// ---- d_ws layout (f16 units): pre-split weights, hi block then lo block.
// w3/w4/cw are PADDED to 16x32 fragment layout (zeros outside valid range) so
// the main kernel loads A-frags unconditionally; zero A entries kill the
// corresponding k-contributions in the MFMA sum regardless of B content.
#define WS_W0 0         // 64x128          -> 8192
#define WS_W1 8192      // 32x64           -> 2048
#define WS_W2 10240     // 16x32           -> 512
#define WS_W3 10752     // 16x32 padded    -> 512
#define WS_W4 11264     // 16x32 padded    -> 512
#define WS_CW 11776     // 16x32 padded    -> 512
#define WS_LO 12288     // lo block at +12288; total 24576 f16 = 48 KB

// ---- LDS layout (f16 units) — unchanged from r10
#define SXH_STR  72             // x-half [128][72] at 0 -> 9216 f16 (dead after L0)
#define SA1_STR  40             // a1 [128][40] at 0     -> ends 5120
#define SA2_OFF  5120           // a2 [128][24]          -> ends 8192
#define SA2_STR  24
#define SA3_OFF  8192           // a3 [128][16] dedicated -> ends 10240
#define SA3_STR  16
#define SA0_OFF  10240          // a0 [128][72]          -> ends 19456
#define SA0_STR  72
#define LDSF16   19456          // 38912 B -> 4 blocks/CU

__device__ __forceinline__ float fast_sigmoid(float v) {
    return __builtin_amdgcn_rcpf(1.0f + __expf(-v));
}
__device__ __forceinline__ float eluf(float v) {
    return v > 0.0f ? v : (__expf(v) - 1.0f);
}
__device__ __forceinline__ f16x4 elu_cvt4(f32x4 a) {
    f16x4 r;
    r[0] = (f16)eluf(a[0]); r[1] = (f16)eluf(a[1]);
    r[2] = (f16)eluf(a[2]); r[3] = (f16)eluf(a[3]);
    return r;
}
// Intra-wave LDS handoff fence (cross-wave safety = disjoint regions).
__device__ __forceinline__ void wave_fence() {
    __builtin_amdgcn_sched_barrier(0);
    __builtin_amdgcn_wave_barrier();
    __builtin_amdgcn_sched_barrier(0);
}

// ---- prep: split all weights into f16 hi + lo once (w ~= hi + lo).
__global__ void prep_split(const float* __restrict__ w0, const float* __restrict__ w1,
                           const float* __restrict__ w2, const float* __restrict__ w3,
                           const float* __restrict__ w4, const float* __restrict__ cw,
                           f16* __restrict__ hi) {
    f16* lo = hi + WS_LO;
    int t = blockIdx.x * 256 + threadIdx.x;
    int stride = gridDim.x * 256;
    for (int i = t; i < 8192; i += stride) {
        float v = w0[i]; f16 h = (f16)v;
        hi[WS_W0 + i] = h; lo[WS_W0 + i] = (f16)(v - (float)h);
    }
    for (int i = t; i < 2048; i += stride) {
        float v = w1[i]; f16 h = (f16)v;
        hi[WS_W1 + i] = h; lo[WS_W1 + i] = (f16)(v - (float)h);
    }
    for (int i = t; i < 512; i += stride) {
        float v = w2[i]; f16 h = (f16)v;
        hi[WS_W2 + i] = h; lo[WS_W2 + i] = (f16)(v - (float)h);
    }
    for (int i = t; i < 512; i += stride) {           // w3 padded: 8x16 valid
        int p = i >> 5, c = i & 31, q = c >> 3, e = c & 7;
        float v = (p < 8 && q < 2) ? w3[p * 16 + q * 8 + e] : 0.0f;
        f16 h = (f16)v;
        hi[WS_W3 + i] = h; lo[WS_W3 + i] = (f16)(v - (float)h);
    }
    for (int i = t; i < 512; i += stride) {           // w4 padded: 4x8 valid
        int p = i >> 5, c = i & 31, q = c >> 3, e = c & 7;
        float v = (p < 4 && q == 0) ? w4[p * 8 + e] : 0.0f;
        f16 h = (f16)v;
        hi[WS_W4 + i] = h; lo[WS_W4 + i] = (f16)(v - (float)h);
    }
    for (int i = t; i < 512; i += stride) {           // cw padded: 3x4 valid
        int p = i >> 5, c = i & 31, q = c >> 3, e = c & 7;
        float v = (p < 3 && q == 0 && e < 4) ? cw[p * 4 + e] : 0.0f;
        f16 h = (f16)v;
        hi[WS_CW + i] = h; lo[WS_CW + i] = (f16)(v - (float)h);
    }
}

// pack 32 f32 -> 4 x f16x8 LDS writes (v_cvt_pkrtz: 1 instr / 2 elems)
__device__ __forceinline__ void pack_write32(const float* v, f16* dst) {
#pragma unroll
    for (int g = 0; g < 4; ++g) {
        f16x8 h;
#pragma unroll
        for (int e = 0; e < 8; e += 2) {
            auto pk = __builtin_amdgcn_cvt_pkrtz(v[g * 8 + e], v[g * 8 + e + 1]);
            h[e] = pk[0]; h[e + 1] = pk[1];
        }
        *(f16x8*)(dst + g * 8) = h;
    }
}

// 256 threads = 4 waves, 128 pixels/block. x staged in 2 channel-halves with
// half-1 register-prefetched before barrier 1. All layers = 16x16x32 f16 MFMA
// with pre-split (hi+lo) weights loaded straight from d_ws (no VALU).
__global__ __launch_bounds__(256, 4)
void lpg_mfma(const float* __restrict__ x, const f16* __restrict__ wsp,
              const float* __restrict__ b0, const float* __restrict__ b1,
              const float* __restrict__ b2, const float* __restrict__ b3,
              const float* __restrict__ b4, const float* __restrict__ cb,
              float* __restrict__ out) {
    __shared__ __align__(16) f16 S[LDSF16];
    f16* SX  = S;                 // x-half; later a1/a2/a3 (disjoint) overlays
    f16* SA0 = S + SA0_OFF;
    const f16* whi = wsp;
    const f16* wlo = wsp + WS_LO;

    const int tid  = threadIdx.x;
    const int wv   = __builtin_amdgcn_readfirstlane(tid >> 6);
    const int lane = tid & 63;
    const int p    = lane & 15;   // MFMA row/col index
    const int q    = lane >> 4;   // k-group / C-row group
    const int pixbase = blockIdx.x * 128;

    // staging: thread (i = tid&127) stages pixel i, 32 channels per half
    const int i    = tid & 127;
    const int csub = (tid >> 7) * 32;          // 0 or 32 within the half
    int pixs = pixbase + i;
    int bbs  = pixs / HW_;
    int hws  = pixs - bbs * HW_;
    const float* xps = x + ((size_t)bbs * 128 + csub) * HW_ + hws;
    f16* dsts = SX + i * SXH_STR + csub;

    // ---- issue ALL x loads up front (h1 latency hides under bar1 + L0-h0)
    float v0[32], v1[32];
#pragma unroll
    for (int k = 0; k < 32; ++k) v0[k] = xps[(size_t)k * HW_];
#pragma unroll
    for (int k = 0; k < 32; ++k) v1[k] = xps[(size_t)(k + 64) * HW_];

    pack_write32(v0, dsts);       // stage half 0

    // ---- layer-0 A-frags for k-half 0 (pure b128 loads from d_ws)
    const int w0row = (wv * 16 + p) * 128 + q * 8;
    f16x8 w0h[2], w0l[2];
#pragma unroll
    for (int kt = 0; kt < 2; ++kt) {
        w0h[kt] = *(const f16x8*)(whi + WS_W0 + w0row + kt * 32);
        w0l[kt] = *(const f16x8*)(wlo + WS_W0 + w0row + kt * 32);
    }
    f32x4 acc[8];
    {
        f32x4 b0v = *(const f32x4*)(b0 + wv * 16 + 4 * q);
#pragma unroll
        for (int t = 0; t < 8; ++t) acc[t] = b0v;
    }
    __syncthreads();   // (1) half 0 staged

#pragma unroll 2
    for (int t = 0; t < 8; ++t) {
        const f16* bp = SX + (t * 16 + p) * SXH_STR + q * 8;
        f16x8 bf0 = *(const f16x8*)(bp);
        f16x8 bf1 = *(const f16x8*)(bp + 32);
        acc[t] = MFMA(w0h[0], bf0, acc[t]); acc[t] = MFMA(w0l[0], bf0, acc[t]);
        acc[t] = MFMA(w0h[1], bf1, acc[t]); acc[t] = MFMA(w0l[1], bf1, acc[t]);
    }
    __syncthreads();   // (2) all waves done reading half 0

    pack_write32(v1, dsts);       // stage half 1 (data already in regs)
#pragma unroll
    for (int kt = 0; kt < 2; ++kt) {   // w0 k-half 1 frags
        w0h[kt] = *(const f16x8*)(whi + WS_W0 + w0row + 64 + kt * 32);
        w0l[kt] = *(const f16x8*)(wlo + WS_W0 + w0row + 64 + kt * 32);
    }
    __syncthreads();   // (3) half 1 staged

#pragma unroll 2
    for (int t = 0; t < 8; ++t) {
        const f16* bp = SX + (t * 16 + p) * SXH_STR + q * 8;
        f16x8 bf0 = *(const f16x8*)(bp);
        f16x8 bf1 = *(const f16x8*)(bp + 32);
        acc[t] = MFMA(w0h[0], bf0, acc[t]); acc[t] = MFMA(w0l[0], bf0, acc[t]);
        acc[t] = MFMA(w0h[1], bf1, acc[t]); acc[t] = MFMA(w0l[1], bf1, acc[t]);
        *(f16x4*)(SA0 + (t * 16 + p) * SA0_STR + wv * 16 + 4 * q) = elu_cvt4(acc[t]);
    }
    __syncthreads();   // (4) a0 complete — last block barrier

    // ================= phase C: wave-private (fences only) =================
    f16x8 w1h[2][2], w1l[2][2];
#pragma unroll
    for (int Mt = 0; Mt < 2; ++Mt)
#pragma unroll
        for (int kt = 0; kt < 2; ++kt) {
            int idx = WS_W1 + (Mt * 16 + p) * 64 + kt * 32 + q * 8;
            w1h[Mt][kt] = *(const f16x8*)(whi + idx);
            w1l[Mt][kt] = *(const f16x8*)(wlo + idx);
        }
    const int fidx = p * 32 + q * 8;
    f16x8 w2h = *(const f16x8*)(whi + WS_W2 + fidx);
    f16x8 w2l = *(const f16x8*)(wlo + WS_W2 + fidx);
    f16x8 w3h = *(const f16x8*)(whi + WS_W3 + fidx);
    f16x8 w3l = *(const f16x8*)(wlo + WS_W3 + fidx);
    f16x8 w4h = *(const f16x8*)(whi + WS_W4 + fidx);
    f16x8 w4l = *(const f16x8*)(wlo + WS_W4 + fidx);
    f16x8 whh = *(const f16x8*)(whi + WS_CW + fidx);
    f16x8 whl = *(const f16x8*)(wlo + WS_CW + fidx);

    const f32x4 z4 = {0.f, 0.f, 0.f, 0.f};
    f32x4 b1v0 = *(const f32x4*)(b1 + 4 * q);
    f32x4 b1v1 = *(const f32x4*)(b1 + 16 + 4 * q);
    f32x4 b2v  = *(const f32x4*)(b2 + 4 * q);
    f32x4 b3v  = *(const f32x4*)(b3 + (q & 1) * 4);
    f32x4 b4v  = *(const f32x4*)(b4);
    float cb0v = cb[0], cb1v = cb[1], cb2v = cb[2];

    const int i0a = wv * 32 + p;        // tile A (nt=0)
    const int i0b = wv * 32 + 16 + p;   // tile B (nt=1)

    // ---- layer 1: 64 -> 32
    {
        f32x4 cA0 = b1v0, cA1 = b1v1, cB0 = b1v0, cB1 = b1v1;
#pragma unroll
        for (int kt = 0; kt < 2; ++kt) {
            f16x8 bfA = *(const f16x8*)(SA0 + i0a * SA0_STR + kt * 32 + q * 8);
            f16x8 bfB = *(const f16x8*)(SA0 + i0b * SA0_STR + kt * 32 + q * 8);
            cA0 = MFMA(w1h[0][kt], bfA, cA0); cA0 = MFMA(w1l[0][kt], bfA, cA0);
            cA1 = MFMA(w1h[1][kt], bfA, cA1); cA1 = MFMA(w1l[1][kt], bfA, cA1);
            cB0 = MFMA(w1h[0][kt], bfB, cB0); cB0 = MFMA(w1l[0][kt], bfB, cB0);
            cB1 = MFMA(w1h[1][kt], bfB, cB1); cB1 = MFMA(w1l[1][kt], bfB, cB1);
        }
        *(f16x4*)(SX + i0a * SA1_STR + 4 * q)      = elu_cvt4(cA0);
        *(f16x4*)(SX + i0a * SA1_STR + 16 + 4 * q) = elu_cvt4(cA1);
        *(f16x4*)(SX + i0b * SA1_STR + 4 * q)      = elu_cvt4(cB0);
        *(f16x4*)(SX + i0b * SA1_STR + 16 + 4 * q) = elu_cvt4(cB1);
    }
    wave_fence();   // a1 handoff (intra-wave cross-lane)

    // ---- layer 2: 32 -> 16
    {
        f16x8 bfA = *(const f16x8*)(SX + i0a * SA1_STR + q * 8);
        f16x8 bfB = *(const f16x8*)(SX + i0b * SA1_STR + q * 8);
        f32x4 cA = b2v, cB = b2v;
        cA = MFMA(w2h, bfA, cA); cA = MFMA(w2l, bfA, cA);
        cB = MFMA(w2h, bfB, cB); cB = MFMA(w2l, bfB, cB);
        *(f16x4*)(SX + SA2_OFF + i0a * SA2_STR + 4 * q) = elu_cvt4(cA);
        *(f16x4*)(SX + SA2_OFF + i0b * SA2_STR + 4 * q) = elu_cvt4(cB);
    }
    wave_fence();   // a2 handoff

    // ---- layer 3: 16 -> 8 (A-frag zero-padded for q>=2 -> B garbage is ok)
    {
        f16x8 bfA = *(const f16x8*)(SX + SA2_OFF + i0a * SA2_STR + (q & 1) * 8);
        f16x8 bfB = *(const f16x8*)(SX + SA2_OFF + i0b * SA2_STR + (q & 1) * 8);
        f32x4 cA = b3v, cB = b3v;          // q>=2 lanes compute junk, never stored
        cA = MFMA(w3h, bfA, cA); cA = MFMA(w3l, bfA, cA);
        cB = MFMA(w3h, bfB, cB); cB = MFMA(w3l, bfB, cB);
        if (q < 2) {
            *(f16x4*)(SX + SA3_OFF + i0a * SA3_STR + 4 * q) = elu_cvt4(cA);
            *(f16x4*)(SX + SA3_OFF + i0b * SA3_STR + 4 * q) = elu_cvt4(cB);
        }
    }
    wave_fence();   // a3 handoff

    // ---- layer 4 (8->4) + head (4->3): a4 stays in registers
    f32x4 cyA, cyB;
    {
        f16x8 bfA = *(const f16x8*)(SX + SA3_OFF + i0a * SA3_STR);
        f16x8 bfB = *(const f16x8*)(SX + SA3_OFF + i0b * SA3_STR);
        f32x4 cA = b4v, cB = b4v;          // q!=0 lanes junk, discarded
        cA = MFMA(w4h, bfA, cA); cA = MFMA(w4l, bfA, cA);
        cB = MFMA(w4h, bfB, cB); cB = MFMA(w4l, bfB, cB);

        f16x8 hA = (f16x8){}, hB = (f16x8){};
        if (q == 0) {
#pragma unroll
            for (int e = 0; e < 4; ++e) {
                hA[e] = (f16)eluf(cA[e]);
                hB[e] = (f16)eluf(cB[e]);
            }
        }
        cyA = z4; cyB = z4;
        if (q == 0) {
            cyA[0] = cb0v; cyA[1] = cb1v; cyA[2] = cb2v;
            cyB[0] = cb0v; cyB[1] = cb1v; cyB[2] = cb2v;
        }
        cyA = MFMA(whh, hA, cyA); cyA = MFMA(whl, hA, cyA);
        cyB = MFMA(whh, hB, cyB); cyB = MFMA(whl, hB, cyB);
    }

    // ---- epilogue: y via shuffle from the q==0 lane of column p ----
#pragma unroll
    for (int nt = 0; nt < 2; ++nt) {
        const int i0 = wv * 32 + nt * 16 + p;
        float y0 = __shfl(nt ? cyB[0] : cyA[0], p);
        float y1 = __shfl(nt ? cyB[1] : cyA[1], p);
        float y2 = __shfl(nt ? cyB[2] : cyA[2], p);

        float theta = 0.5235987756f * fast_sigmoid(y0);   // pi/6
        float phi   = 6.2831853072f * fast_sigmoid(y1);   // 2*pi
        float dist  = 83.0f         * fast_sigmoid(y2);
        float st = __sinf(theta), ct = __cosf(theta);
        float sp = __sinf(phi),   cp = __cosf(phi);
        float n1 = st * cp, n2 = st * sp, n3 = ct;
        float inv = __frsqrt_rn(fmaf(n1, n1, fmaf(n2, n2, n3 * n3)));
        n1 *= inv; n2 *= inv; n3 *= inv;

        const float ksc = 1.0f / (8.0f * 715.0f);
        float nu[8];
#pragma unroll
        for (int j = 0; j < 8; ++j) nu[j] = n1 * (((float)j - 3.5f) * ksc);

        int pix = pixbase + i0;
        int bb  = pix / HW_;
        int hw  = pix - bb * HW_;
        int hh  = hw / W_;
        int ww  = hw - hh * W_;
        const int obase = bb * OHW_ + (hh * 8) * OW_ + ww * 8;
#pragma unroll
        for (int r = 0; r < 2; ++r) {
            int irow = q * 2 + r;               // lane (p,q) writes rows 2q,2q+1
            float base = fmaf(n2, ((float)irow - 3.5f) * ksc, n3);
            float4 r0, r1;
            r0.x = dist * __builtin_amdgcn_rcpf(base + nu[0]);
            r0.y = dist * __builtin_amdgcn_rcpf(base + nu[1]);
            r0.z = dist * __builtin_amdgcn_rcpf(base + nu[2]);
            r0.w = dist * __builtin_amdgcn_rcpf(base + nu[3]);
            r1.x = dist * __builtin_amdgcn_rcpf(base + nu[4]);
            r1.y = dist * __builtin_amdgcn_rcpf(base + nu[5]);
            r1.z = dist * __builtin_amdgcn_rcpf(base + nu[6]);
            r1.w = dist * __builtin_amdgcn_rcpf(base + nu[7]);
            float4* op = (float4*)(out + obase + irow * OW_);
            op[0] = r0;
            op[1] = r1;
        }
    }
}

extern "C" void kernel_launch(void* const* d_in, const int* in_sizes, int n_in,
                              void* d_out, int out_size, void* d_ws, size_t ws_size,
                              hipStream_t stream) {
    const float* x  = (const float*)d_in[0];
    const float* w0 = (const float*)d_in[1];
    const float* b0 = (const float*)d_in[2];
    const float* w1 = (const float*)d_in[3];
    const float* b1 = (const float*)d_in[4];
    const float* w2 = (const float*)d_in[5];
    const float* b2 = (const float*)d_in[6];
    const float* w3 = (const float*)d_in[7];
    const float* b3 = (const float*)d_in[8];
    const float* w4 = (const float*)d_in[9];
    const float* b4 = (const float*)d_in[10];
    const float* cw = (const float*)d_in[11];
    const float* cb = (const float*)d_in[12];
    f16* wsp   = (f16*)d_ws;
    float* outp = (float*)d_out;

    prep_split<<<32, 256, 0, stream>>>(w0, w1, w2, w3, w4, cw, wsp);
    lpg_mfma<<<NPIX / 128, 256, 0, stream>>>(x, wsp, b0, b1, b2, b3, b4, cb, outp);
}

// Round 13
// 31.025 us; speedup vs baseline: 1.0428x; 1.0428x over previous
//
#include <hip/hip_runtime.h>
#include <math.h>

#define HW_   6688      // 44*152
#define W_    152
#define NPIX  107008    // 16*44*152
#define OW_   1216      // 152*8
#define OHW_  428032    // 352*1216

typedef _Float16 f16;
typedef _Float16 f16x2 __attribute__((ext_vector_type(2)));
typedef _Float16 f16x4 __attribute__((ext_vector_type(4)));
typedef _Float16 f16x8 __attribute__((ext_vector_type(8)));
typedef float    f32x4 __attribute__((ext_vector_type(4)));

#define MFMA(a,b,c) __builtin_amdgcn_mfma_f32_16x16x32_f16((a),(b),(c),0,0,0)

// ---- LDS layout (f16 units) — r10 layout. x rows are PERMUTED: pixel i
// lives in row (i>>1) | ((i&1)<<6)  (even pixels rows 0..63, odd 64..127) so
// pixel-pair staging writes land 2-way-conflict-free (free per m136).
#define SXH_STR  72             // x-half [128][72] at 0 -> 9216 f16 (dead after L0)
#define SA1_STR  40             // a1 [128][40] at 0     -> ends 5120
#define SA2_OFF  5120           // a2 [128][24]          -> ends 8192
#define SA2_STR  24
#define SA3_OFF  8192           // a3 [128][16] dedicated -> ends 10240
#define SA3_STR  16
#define SA0_OFF  10240          // a0 [128][72]          -> ends 19456
#define SA0_STR  72
#define LDSF16   19456          // 38912 B -> 4 blocks/CU

__device__ __forceinline__ float fast_sigmoid(float v) {
    return __builtin_amdgcn_rcpf(1.0f + __expf(-v));
}
__device__ __forceinline__ float eluf(float v) {
    return v > 0.0f ? v : (__expf(v) - 1.0f);
}
// split fp32 -> fp16 hi + fp16 lo (w ~= hi + lo)
__device__ __forceinline__ void split8(const float* v, f16x8& hi, f16x8& lo) {
#pragma unroll
    for (int e = 0; e < 8; ++e) {
        f16 h = (f16)v[e];
        hi[e] = h;
        lo[e] = (f16)(v[e] - (float)h);
    }
}
__device__ __forceinline__ f16x4 elu_cvt4(f32x4 a) {
    f16x4 r;
    r[0] = (f16)eluf(a[0]); r[1] = (f16)eluf(a[1]);
    r[2] = (f16)eluf(a[2]); r[3] = (f16)eluf(a[3]);
    return r;
}
// pack 4 floats (2 channel-pairs for 2 pixels) via cvt_pkrtz into f16x4s
__device__ __forceinline__ f16x4 pk4(float a, float b, float c, float d) {
    auto p0 = __builtin_amdgcn_cvt_pkrtz(a, b);   // __fp16 vec
    auto p1 = __builtin_amdgcn_cvt_pkrtz(c, d);
    f16x4 r;
    r[0] = (f16)p0[0]; r[1] = (f16)p0[1];
    r[2] = (f16)p1[0]; r[3] = (f16)p1[1];
    return r;
}
// Intra-wave LDS handoff fence (cross-wave safety = disjoint regions).
__device__ __forceinline__ void wave_fence() {
    __builtin_amdgcn_sched_barrier(0);
    __builtin_amdgcn_wave_barrier();
    __builtin_amdgcn_sched_barrier(0);
}

// 256 threads = 4 waves, 128 pixels/block. x staged in 2 channel-halves with
// float2 pixel-pair loads (512B/wave-request) + f16x4 ds_write_b64 packs.
// All layers = 16x16x32 f16 MFMA with split (hi+lo) weights. After the a0
// block-barrier, phase C is wave-private (wave fences, disjoint regions).
__global__ __launch_bounds__(256, 4)
void lpg_mfma(const float* __restrict__ x,
              const float* __restrict__ w0, const float* __restrict__ b0,
              const float* __restrict__ w1, const float* __restrict__ b1,
              const float* __restrict__ w2, const float* __restrict__ b2,
              const float* __restrict__ w3, const float* __restrict__ b3,
              const float* __restrict__ w4, const float* __restrict__ b4,
              const float* __restrict__ cw, const float* __restrict__ cb,
              float* __restrict__ out) {
    __shared__ __align__(16) f16 S[LDSF16];
    f16* SX  = S;                 // x-half (permuted rows); later a1/a2/a3
    f16* SA0 = S + SA0_OFF;

    const int tid  = threadIdx.x;
    const int wv   = __builtin_amdgcn_readfirstlane(tid >> 6);
    const int lane = tid & 63;
    const int p    = lane & 15;   // MFMA row/col index
    const int q    = lane >> 4;   // k-group / C-row group
    const int pixbase = blockIdx.x * 128;

    // ---- staging geometry: thread handles pixel pair (2*p2, 2*p2+1);
    // channel group base = wv*4, stepping by 16 per u (4 waves x 4 channels).
    const int p2 = lane;                       // pair index 0..63 (wave covers all)
    int pix0 = pixbase + 2 * p2;
    int bbs  = pix0 / HW_;
    int hws  = pix0 - bbs * HW_;               // even -> float2 is 8B aligned
    const float* xb = x + (size_t)bbs * 128 * HW_ + hws;
    f16* dr0 = SX + p2 * SXH_STR;              // row of even pixel
    f16* dr1 = SX + (64 + p2) * SXH_STR;       // row of odd pixel

    // ---- stage half 0 (channels 0..63): 16 float2 loads, 8 b64 writes
#pragma unroll
    for (int u = 0; u < 4; ++u) {
        int c = (wv + u * 4) * 4;              // local column 0..60
        const float* s = xb + (size_t)c * HW_;
        float2 a0 = *(const float2*)(s);
        float2 a1 = *(const float2*)(s + HW_);
        float2 a2 = *(const float2*)(s + 2 * (size_t)HW_);
        float2 a3 = *(const float2*)(s + 3 * (size_t)HW_);
        *(f16x4*)(dr0 + c) = pk4(a0.x, a1.x, a2.x, a3.x);
        *(f16x4*)(dr1 + c) = pk4(a0.y, a1.y, a2.y, a3.y);
    }

    // ---- layer-0 weights for k-half 0 + bias; accs for all 8 pixel tiles
    const int w0row = (wv * 16 + p) * 128 + q * 8;
    f16x8 w0h[2], w0l[2];
#pragma unroll
    for (int kt = 0; kt < 2; ++kt) {
        float v[8];
#pragma unroll
        for (int e = 0; e < 8; ++e) v[e] = w0[w0row + kt * 32 + e];
        split8(v, w0h[kt], w0l[kt]);
    }
    f32x4 acc[8];
    {
        f32x4 b0v = *(const f32x4*)(b0 + wv * 16 + 4 * q);
#pragma unroll
        for (int t = 0; t < 8; ++t) acc[t] = b0v;
    }
    // x-row within a tile for MFMA B-frag: pixel t*16+p -> permuted row
    const int xrow = (p >> 1) + 64 * (p & 1);  // + t*8 per tile

    __syncthreads();   // (1) half 0 staged

#pragma unroll 2
    for (int t = 0; t < 8; ++t) {
        const f16* bp = SX + (t * 8 + xrow) * SXH_STR + q * 8;
        f16x8 bf0 = *(const f16x8*)(bp);
        f16x8 bf1 = *(const f16x8*)(bp + 32);
        acc[t] = MFMA(w0h[0], bf0, acc[t]); acc[t] = MFMA(w0l[0], bf0, acc[t]);
        acc[t] = MFMA(w0h[1], bf1, acc[t]); acc[t] = MFMA(w0l[1], bf1, acc[t]);
    }
    __syncthreads();   // (2) all waves done reading half 0

    // ---- stage half 1 (channels 64..127) over the same buffer
#pragma unroll
    for (int u = 0; u < 4; ++u) {
        int c = (wv + u * 4) * 4;
        const float* s = xb + (size_t)(64 + c) * HW_;
        float2 a0 = *(const float2*)(s);
        float2 a1 = *(const float2*)(s + HW_);
        float2 a2 = *(const float2*)(s + 2 * (size_t)HW_);
        float2 a3 = *(const float2*)(s + 3 * (size_t)HW_);
        *(f16x4*)(dr0 + c) = pk4(a0.x, a1.x, a2.x, a3.x);
        *(f16x4*)(dr1 + c) = pk4(a0.y, a1.y, a2.y, a3.y);
    }
#pragma unroll
    for (int kt = 0; kt < 2; ++kt) {     // w0 k-half 1 (reuses registers)
        float v[8];
#pragma unroll
        for (int e = 0; e < 8; ++e) v[e] = w0[w0row + 64 + kt * 32 + e];
        split8(v, w0h[kt], w0l[kt]);
    }
    __syncthreads();   // (3) half 1 staged

#pragma unroll 2
    for (int t = 0; t < 8; ++t) {
        const f16* bp = SX + (t * 8 + xrow) * SXH_STR + q * 8;
        f16x8 bf0 = *(const f16x8*)(bp);
        f16x8 bf1 = *(const f16x8*)(bp + 32);
        acc[t] = MFMA(w0h[0], bf0, acc[t]); acc[t] = MFMA(w0l[0], bf0, acc[t]);
        acc[t] = MFMA(w0h[1], bf1, acc[t]); acc[t] = MFMA(w0l[1], bf1, acc[t]);
        *(f16x4*)(SA0 + (t * 16 + p) * SA0_STR + wv * 16 + 4 * q) = elu_cvt4(acc[t]);
    }
    __syncthreads();   // (4) a0 complete — last block barrier

    // ================= phase C: wave-private (fences only) =================
    f16x8 w1h[2][2], w1l[2][2];
#pragma unroll
    for (int Mt = 0; Mt < 2; ++Mt)
#pragma unroll
        for (int kt = 0; kt < 2; ++kt) {
            float v[8];
#pragma unroll
            for (int e = 0; e < 8; ++e) v[e] = w1[(Mt * 16 + p) * 64 + kt * 32 + q * 8 + e];
            split8(v, w1h[Mt][kt], w1l[Mt][kt]);
        }
    f16x8 w2h, w2l;
    {
        float v[8];
#pragma unroll
        for (int e = 0; e < 8; ++e) v[e] = w2[p * 32 + q * 8 + e];
        split8(v, w2h, w2l);
    }
    f16x8 w3h, w3l;
    {
        float v[8];
        bool ok = (p < 8) && (q < 2);
#pragma unroll
        for (int e = 0; e < 8; ++e) v[e] = ok ? w3[p * 16 + q * 8 + e] : 0.0f;
        split8(v, w3h, w3l);
    }
    f16x8 w4h, w4l;
    {
        float v[8];
        bool ok = (p < 4) && (q == 0);
#pragma unroll
        for (int e = 0; e < 8; ++e) v[e] = ok ? w4[p * 8 + e] : 0.0f;
        split8(v, w4h, w4l);
    }
    f16x8 whh, whl;
    {
        float v[8];
        bool ok = (p < 3) && (q == 0);
#pragma unroll
        for (int e = 0; e < 8; ++e) v[e] = (ok && e < 4) ? cw[p * 4 + e] : 0.0f;
        split8(v, whh, whl);
    }
    const f32x4 z4 = {0.f, 0.f, 0.f, 0.f};
    f32x4 b1v0 = *(const f32x4*)(b1 + 4 * q);
    f32x4 b1v1 = *(const f32x4*)(b1 + 16 + 4 * q);
    f32x4 b2v  = *(const f32x4*)(b2 + 4 * q);
    f32x4 b3v  = *(const f32x4*)(b3 + (q & 1) * 4);
    f32x4 b4v  = *(const f32x4*)(b4);
    float cb0v = cb[0], cb1v = cb[1], cb2v = cb[2];

    const int i0a = wv * 32 + p;        // tile A (nt=0)
    const int i0b = wv * 32 + 16 + p;   // tile B (nt=1)

    // ---- layer 1: 64 -> 32
    {
        f32x4 cA0 = b1v0, cA1 = b1v1, cB0 = b1v0, cB1 = b1v1;
#pragma unroll
        for (int kt = 0; kt < 2; ++kt) {
            f16x8 bfA = *(const f16x8*)(SA0 + i0a * SA0_STR + kt * 32 + q * 8);
            f16x8 bfB = *(const f16x8*)(SA0 + i0b * SA0_STR + kt * 32 + q * 8);
            cA0 = MFMA(w1h[0][kt], bfA, cA0); cA0 = MFMA(w1l[0][kt], bfA, cA0);
            cA1 = MFMA(w1h[1][kt], bfA, cA1); cA1 = MFMA(w1l[1][kt], bfA, cA1);
            cB0 = MFMA(w1h[0][kt], bfB, cB0); cB0 = MFMA(w1l[0][kt], bfB, cB0);
            cB1 = MFMA(w1h[1][kt], bfB, cB1); cB1 = MFMA(w1l[1][kt], bfB, cB1);
        }
        *(f16x4*)(SX + i0a * SA1_STR + 4 * q)      = elu_cvt4(cA0);
        *(f16x4*)(SX + i0a * SA1_STR + 16 + 4 * q) = elu_cvt4(cA1);
        *(f16x4*)(SX + i0b * SA1_STR + 4 * q)      = elu_cvt4(cB0);
        *(f16x4*)(SX + i0b * SA1_STR + 16 + 4 * q) = elu_cvt4(cB1);
    }
    wave_fence();   // a1 handoff (intra-wave cross-lane)

    // ---- layer 2: 32 -> 16
    {
        f16x8 bfA = *(const f16x8*)(SX + i0a * SA1_STR + q * 8);
        f16x8 bfB = *(const f16x8*)(SX + i0b * SA1_STR + q * 8);
        f32x4 cA = b2v, cB = b2v;
        cA = MFMA(w2h, bfA, cA); cA = MFMA(w2l, bfA, cA);
        cB = MFMA(w2h, bfB, cB); cB = MFMA(w2l, bfB, cB);
        *(f16x4*)(SX + SA2_OFF + i0a * SA2_STR + 4 * q) = elu_cvt4(cA);
        *(f16x4*)(SX + SA2_OFF + i0b * SA2_STR + 4 * q) = elu_cvt4(cB);
    }
    wave_fence();   // a2 handoff

    // ---- layer 3: 16 -> 8 (K valid for q<2); a3 in its own region
    {
        f16x8 bfA = *(const f16x8*)(SX + SA2_OFF + i0a * SA2_STR + (q & 1) * 8);
        f16x8 bfB = *(const f16x8*)(SX + SA2_OFF + i0b * SA2_STR + (q & 1) * 8);
        if (q >= 2) { bfA = (f16x8){}; bfB = (f16x8){}; }
        f32x4 cA = (q < 2) ? b3v : z4, cB = (q < 2) ? b3v : z4;
        cA = MFMA(w3h, bfA, cA); cA = MFMA(w3l, bfA, cA);
        cB = MFMA(w3h, bfB, cB); cB = MFMA(w3l, bfB, cB);
        if (q < 2) {
            *(f16x4*)(SX + SA3_OFF + i0a * SA3_STR + 4 * q) = elu_cvt4(cA);
            *(f16x4*)(SX + SA3_OFF + i0b * SA3_STR + 4 * q) = elu_cvt4(cB);
        }
    }
    wave_fence();   // a3 handoff

    // ---- layer 4 (8->4) + head (4->3): a4 stays in registers
    f32x4 cyA, cyB;
    {
        f16x8 bfA = *(const f16x8*)(SX + SA3_OFF + i0a * SA3_STR);
        f16x8 bfB = *(const f16x8*)(SX + SA3_OFF + i0b * SA3_STR);
        if (q != 0) { bfA = (f16x8){}; bfB = (f16x8){}; }
        f32x4 cA = (q == 0) ? b4v : z4, cB = (q == 0) ? b4v : z4;
        cA = MFMA(w4h, bfA, cA); cA = MFMA(w4l, bfA, cA);
        cB = MFMA(w4h, bfB, cB); cB = MFMA(w4l, bfB, cB);

        f16x8 hA = (f16x8){}, hB = (f16x8){};
        if (q == 0) {
#pragma unroll
            for (int e = 0; e < 4; ++e) {
                hA[e] = (f16)eluf(cA[e]);
                hB[e] = (f16)eluf(cB[e]);
            }
        }
        cyA = z4; cyB = z4;
        if (q == 0) {
            cyA[0] = cb0v; cyA[1] = cb1v; cyA[2] = cb2v;
            cyB[0] = cb0v; cyB[1] = cb1v; cyB[2] = cb2v;
        }
        cyA = MFMA(whh, hA, cyA); cyA = MFMA(whl, hA, cyA);
        cyB = MFMA(whh, hB, cyB); cyB = MFMA(whl, hB, cyB);
    }

    // ---- epilogue: y via shuffle from the q==0 lane of column p ----
#pragma unroll
    for (int nt = 0; nt < 2; ++nt) {
        const int i0 = wv * 32 + nt * 16 + p;
        float y0 = __shfl(nt ? cyB[0] : cyA[0], p);
        float y1 = __shfl(nt ? cyB[1] : cyA[1], p);
        float y2 = __shfl(nt ? cyB[2] : cyA[2], p);

        float theta = 0.5235987756f * fast_sigmoid(y0);   // pi/6
        float phi   = 6.2831853072f * fast_sigmoid(y1);   // 2*pi
        float dist  = 83.0f         * fast_sigmoid(y2);
        float st = __sinf(theta), ct = __cosf(theta);
        float sp = __sinf(phi),   cp = __cosf(phi);
        float n1 = st * cp, n2 = st * sp, n3 = ct;
        float inv = __frsqrt_rn(fmaf(n1, n1, fmaf(n2, n2, n3 * n3)));
        n1 *= inv; n2 *= inv; n3 *= inv;

        const float ksc = 1.0f / (8.0f * 715.0f);
        float nu[8];
#pragma unroll
        for (int j = 0; j < 8; ++j) nu[j] = n1 * (((float)j - 3.5f) * ksc);

        int pix = pixbase + i0;
        int bb  = pix / HW_;
        int hw  = pix - bb * HW_;
        int hh  = hw / W_;
        int ww  = hw - hh * W_;
        const int obase = bb * OHW_ + (hh * 8) * OW_ + ww * 8;
#pragma unroll
        for (int r = 0; r < 2; ++r) {
            int irow = q * 2 + r;               // lane (p,q) writes rows 2q,2q+1
            float base = fmaf(n2, ((float)irow - 3.5f) * ksc, n3);
            float4 r0, r1;
            r0.x = dist * __builtin_amdgcn_rcpf(base + nu[0]);
            r0.y = dist * __builtin_amdgcn_rcpf(base + nu[1]);
            r0.z = dist * __builtin_amdgcn_rcpf(base + nu[2]);
            r0.w = dist * __builtin_amdgcn_rcpf(base + nu[3]);
            r1.x = dist * __builtin_amdgcn_rcpf(base + nu[4]);
            r1.y = dist * __builtin_amdgcn_rcpf(base + nu[5]);
            r1.z = dist * __builtin_amdgcn_rcpf(base + nu[6]);
            r1.w = dist * __builtin_amdgcn_rcpf(base + nu[7]);
            float4* op = (float4*)(out + obase + irow * OW_);
            op[0] = r0;
            op[1] = r1;
        }
    }
}

extern "C" void kernel_launch(void* const* d_in, const int* in_sizes, int n_in,
                              void* d_out, int out_size, void* d_ws, size_t ws_size,
                              hipStream_t stream) {
    const float* x  = (const float*)d_in[0];
    const float* w0 = (const float*)d_in[1];
    const float* b0 = (const float*)d_in[2];
    const float* w1 = (const float*)d_in[3];
    const float* b1 = (const float*)d_in[4];
    const float* w2 = (const float*)d_in[5];
    const float* b2 = (const float*)d_in[6];
    const float* w3 = (const float*)d_in[7];
    const float* b3 = (const float*)d_in[8];
    const float* w4 = (const float*)d_in[9];
    const float* b4 = (const float*)d_in[10];
    const float* cw = (const float*)d_in[11];
    const float* cb = (const float*)d_in[12];
    float* outp = (float*)d_out;

    lpg_mfma<<<NPIX / 128, 256, 0, stream>>>(x, w0, b0, w1, b1, w2, b2, w3, b3,
                                             w4, b4, cw, cb, outp);
}